// Round 3
// baseline (2199.320 us; speedup 1.0000x reference)
//
#include <hip/hip_runtime.h>
#include <math.h>

// Problem constants (B=10240, D=512, M=8, L=3)
#define BB   10240
#define DD   512
#define MM   8
#define SK   2          // split-K factor (jc halves)

typedef _Float16 h8 __attribute__((ext_vector_type(8)));
typedef float    f4 __attribute__((ext_vector_type(4)));

// async global->LDS DMA, 16 B per lane; LDS dst = wave-uniform base + lane*16
__device__ __forceinline__ void gload16(const void* g, void* l) {
    __builtin_amdgcn_global_load_lds(
        (__attribute__((address_space(1))) void*)(g),
        (__attribute__((address_space(3))) void*)(l), 16, 0, 0);
}

// ---------------- fp32 -> fp16 convert (8 elems/thread) ----------------
__global__ void __launch_bounds__(256) cvt_f32_f16(const float* __restrict__ s,
                                                   _Float16* __restrict__ d, int n8) {
    int i = blockIdx.x * 256 + threadIdx.x;
    if (i >= n8) return;
    const float4* sp = (const float4*)s + (size_t)i * 2;
    float4 a = sp[0], b = sp[1];
    h8 o = { (_Float16)a.x, (_Float16)a.y, (_Float16)a.z, (_Float16)a.w,
             (_Float16)b.x, (_Float16)b.y, (_Float16)b.z, (_Float16)b.w };
    *(h8*)(d + (size_t)i * 8) = o;
}

// ---------------- zero fp32 buffer (16 elems/thread) ----------------
__global__ void __launch_bounds__(256) zero_k(float* __restrict__ p) {
    size_t i = ((size_t)blockIdx.x * 256 + threadIdx.x) * 16;
    float4 z = make_float4(0.f, 0.f, 0.f, 0.f);
    float4* q = (float4*)(p + i);
    q[0] = z; q[1] = z; q[2] = z; q[3] = z;
}

// ---------------- split-K GEMM core ----------------
// accb[b,i] += sum_{jc in half} sum_m pW[b,m] * W[m,i,j] * x[b,j]   (fp32 atomic)
// Tile BM=128, BN=64, BK=64; grid (8, 80, SK); 32 barriers/block.
// A (x tile) single-buffered: frags loaded to regs at mi==0, next jc's A DMA
// issued at mi==1 (barrier-separated). W double-buffered, 8 KB per stage.
// XOR swizzle (16B chunk ^ row) applied on the GLOBAL address -> 2-way max
// LDS bank aliasing (free) and wave-uniform+lane*16 DMA layout preserved.
__global__ void __launch_bounds__(256, 4) gemm_sk(
    const _Float16* __restrict__ xh,   // (B,512) fp16
    const _Float16* __restrict__ Wh,   // (8,512,512) fp16
    const float*  __restrict__ pW,     // (B,8)
    float* __restrict__ accb)          // (B,512) fp32, pre-zeroed
{
    __shared__ __align__(16) _Float16 Abuf[128 * 64];     // 16 KB
    __shared__ __align__(16) _Float16 Bbuf[2][64 * 64];   // 2 x 8 KB

    const int tid  = threadIdx.x;
    const int lane = tid & 63;
    const int w    = tid >> 6;
    const int wm   = w >> 1, wn = w & 1;
    const int ln16 = lane & 15, quad = lane >> 4;
    const int bn0  = blockIdx.x * 64;
    const int bm0  = blockIdx.y * 128;
    const int jc0  = blockIdx.z * (8 / SK);

    // per-lane pW for this wave's 4 A-row groups, all 8 m, as fp16
    _Float16 pwh[4][8];
    #pragma unroll
    for (int mt = 0; mt < 4; ++mt) {
        const float* pp = pW + (size_t)(bm0 + wm * 64 + mt * 16 + ln16) * MM;
        float4 p0 = *(const float4*)pp;
        float4 p1 = *(const float4*)(pp + 4);
        pwh[mt][0] = (_Float16)p0.x; pwh[mt][1] = (_Float16)p0.y;
        pwh[mt][2] = (_Float16)p0.z; pwh[mt][3] = (_Float16)p0.w;
        pwh[mt][4] = (_Float16)p1.x; pwh[mt][5] = (_Float16)p1.y;
        pwh[mt][6] = (_Float16)p1.z; pwh[mt][7] = (_Float16)p1.w;
    }

    auto stageA = [&](int jc) {
        #pragma unroll
        for (int c = 0; c < 4; ++c) {
            int rbase   = w * 32 + c * 8;
            int row     = rbase + (lane >> 3);
            int logical = (lane & 7) ^ (row & 7);
            gload16(xh + (size_t)(bm0 + row) * DD + jc * 64 + logical * 8,
                    &Abuf[rbase * 64]);
        }
    };
    auto stageW = [&](int buf, int m, int jc) {
        #pragma unroll
        for (int c = 0; c < 2; ++c) {
            int rbase   = w * 16 + c * 8;
            int row     = rbase + (lane >> 3);
            int logical = (lane & 7) ^ (row & 7);
            gload16(Wh + (size_t)m * (DD * DD) + (size_t)(bn0 + row) * DD
                       + jc * 64 + logical * 8,
                    &Bbuf[buf][rbase * 64]);
        }
    };

    f4 acc[4][2] = {};
    h8 af[2][4];

    stageA(jc0);
    stageW(0, 0, jc0);

    for (int j2 = 0; j2 < 8 / SK; ++j2) {
        const int jc = jc0 + j2;
        #pragma unroll
        for (int mi = 0; mi < 8; ++mi) {
            __syncthreads();   // drains prior DMA (vmcnt(0)) + LDS reads

            if (mi == 0) {     // A frags -> regs; Abuf free after next barrier
                #pragma unroll
                for (int ks = 0; ks < 2; ++ks)
                    #pragma unroll
                    for (int mt = 0; mt < 4; ++mt) {
                        int row  = wm * 64 + mt * 16 + ln16;
                        int phys = (ks * 4 + quad) ^ (row & 7);
                        af[ks][mt] = *(const h8*)&Abuf[row * 64 + phys * 8];
                    }
            }
            if (mi == 1 && j2 < 8 / SK - 1) stageA(jc + 1);
            if (mi < 7)                  stageW((mi + 1) & 1, mi + 1, jc);
            else if (j2 < 8 / SK - 1)    stageW(0, 0, jc + 1);

            h8 bfr[2][2];
            #pragma unroll
            for (int ks = 0; ks < 2; ++ks)
                #pragma unroll
                for (int nt = 0; nt < 2; ++nt) {
                    int row  = wn * 32 + nt * 16 + ln16;
                    int phys = (ks * 4 + quad) ^ (row & 7);
                    bfr[ks][nt] = *(const h8*)&Bbuf[mi & 1][row * 64 + phys * 8];
                }

            #pragma unroll
            for (int ks = 0; ks < 2; ++ks)
                #pragma unroll
                for (int mt = 0; mt < 4; ++mt) {
                    h8 as = af[ks][mt] * pwh[mt][mi];   // v_pk_mul_f16 x4
                    #pragma unroll
                    for (int nt = 0; nt < 2; ++nt)
                        acc[mt][nt] = __builtin_amdgcn_mfma_f32_16x16x32_f16(
                            as, bfr[ks][nt], acc[mt][nt], 0, 0, 0);
                }
        }
    }

    // ---- epilogue: raw partial accumulate (gate/bias applied in finish_k) ----
    const int i0 = bn0 + wn * 32 + ln16;
    const int i1 = i0 + 16;
    #pragma unroll
    for (int mt = 0; mt < 4; ++mt)
        #pragma unroll
        for (int r = 0; r < 4; ++r) {
            int b = bm0 + wm * 64 + mt * 16 + quad * 4 + r;
            atomicAdd(accb + (size_t)b * DD + i0, acc[mt][0][r]);
            atomicAdd(accb + (size_t)b * DD + i1, acc[mt][1][r]);
        }
}

// ---------------- finish: gate + bias (+ LayerNorm + ELU) ----------------
// h[b,i] = gW[b,i]*acc[b,i] + gb[b,i]*sum_m pb[b,m]*bs[m,i]
// DO_LN: LN(no affine)+ELU -> fp16 outh; else fp32 outf (may alias acc).
template <int DO_LN>
__global__ void __launch_bounds__(256) finish_k(
    const float* __restrict__ acc,   // (B,512) raw dot
    const float* __restrict__ gW,    // (B,512)
    const float* __restrict__ gb,    // (B,512)
    const float* __restrict__ pb,    // (B,8)
    const float* __restrict__ bsv,   // (8,512)
    float* __restrict__ outf, _Float16* __restrict__ outh) {
    const int w    = threadIdx.x >> 6;
    const int lane = threadIdx.x & 63;
    const int row  = blockIdx.x * 4 + w;
    const int i0   = lane * 8;

    const float* ap = acc + (size_t)row * DD + i0;
    float a[8];
    *(float4*)a       = *(const float4*)ap;
    *(float4*)(a + 4) = *(const float4*)(ap + 4);

    float4 q0 = *(const float4*)(pb + (size_t)row * MM);
    float4 q1 = *(const float4*)(pb + (size_t)row * MM + 4);
    float pbv[8] = { q0.x, q0.y, q0.z, q0.w, q1.x, q1.y, q1.z, q1.w };

    float bias[8] = {};
    #pragma unroll
    for (int m = 0; m < 8; ++m) {
        const float* bp = bsv + m * DD + i0;
        float4 b0 = *(const float4*)bp, b1 = *(const float4*)(bp + 4);
        float bb[8] = { b0.x, b0.y, b0.z, b0.w, b1.x, b1.y, b1.z, b1.w };
        #pragma unroll
        for (int j = 0; j < 8; ++j) bias[j] += pbv[m] * bb[j];
    }

    const float* gwp = gW + (size_t)row * DD + i0;
    const float* gbp = gb + (size_t)row * DD + i0;
    float4 w0 = *(const float4*)gwp, w1 = *(const float4*)(gwp + 4);
    float4 g0 = *(const float4*)gbp, g1 = *(const float4*)(gbp + 4);
    float gw[8] = { w0.x, w0.y, w0.z, w0.w, w1.x, w1.y, w1.z, w1.w };
    float gg[8] = { g0.x, g0.y, g0.z, g0.w, g1.x, g1.y, g1.z, g1.w };

    float h[8];
    #pragma unroll
    for (int j = 0; j < 8; ++j) h[j] = gw[j] * a[j] + gg[j] * bias[j];

    if (DO_LN) {
        float s = 0.f, q = 0.f;
        #pragma unroll
        for (int j = 0; j < 8; ++j) { s += h[j]; q += h[j] * h[j]; }
        #pragma unroll
        for (int off = 1; off < 64; off <<= 1) {
            s += __shfl_xor(s, off);
            q += __shfl_xor(q, off);
        }
        float mu   = s * (1.0f / 512.0f);
        float var  = q * (1.0f / 512.0f) - mu * mu;
        float rstd = rsqrtf(var + 1e-5f);
        h8 o;
        #pragma unroll
        for (int j = 0; j < 8; ++j) {
            float t = (h[j] - mu) * rstd;
            t = t > 0.0f ? t : expm1f(t);
            o[j] = (_Float16)t;
        }
        *(h8*)(outh + (size_t)row * DD + i0) = o;
    } else {
        float* op = outf + (size_t)row * DD + i0;
        *(float4*)op       = make_float4(h[0], h[1], h[2], h[3]);
        *(float4*)(op + 4) = make_float4(h[4], h[5], h[6], h[7]);
    }
}

extern "C" void kernel_launch(void* const* d_in, const int* in_sizes, int n_in,
                              void* d_out, int out_size, void* d_ws, size_t ws_size,
                              hipStream_t stream) {
    const float* x   = (const float*)d_in[0];   // (B,512)
    const float* Ws  = (const float*)d_in[1];   // (3,8,512,512)
    const float* bs  = (const float*)d_in[2];   // (3,8,512)
    const float* pWs = (const float*)d_in[3];   // (3,B,8)
    const float* pbs = (const float*)d_in[4];   // (3,B,8)
    const float* gWs = (const float*)d_in[5];   // (3,B,512,1)
    const float* gbs = (const float*)d_in[6];   // (3,B,512)
    float* out = (float*)d_out;                 // (B,512); also per-layer fp32 acc

    // workspace: Wh 12.58 MB + xh 10.49 MB = 23.1 MB
    _Float16* Wh = (_Float16*)d_ws;
    _Float16* xh = Wh + (size_t)3 * MM * DD * DD;

    const int wsl = MM * DD * DD;
    const int bsl = MM * DD;
    const int pl  = BB * MM;
    const int gl  = BB * DD;

    cvt_f32_f16<<<3072, 256, 0, stream>>>(Ws, Wh, 786432);   // 3*8*512*512/8
    cvt_f32_f16<<<2560, 256, 0, stream>>>(x, xh, 655360);    // B*512/8

    dim3 gg(DD / 64, BB / 128, SK);      // (8, 80, 2)
    const int zgrid = BB * DD / (256 * 16);   // 1280

    // layer 0
    zero_k<<<zgrid, 256, 0, stream>>>(out);
    gemm_sk<<<gg, 256, 0, stream>>>(xh, Wh, pWs, out);
    finish_k<1><<<BB / 4, 256, 0, stream>>>(out, gWs, gbs, pbs, bs, nullptr, xh);
    // layer 1
    zero_k<<<zgrid, 256, 0, stream>>>(out);
    gemm_sk<<<gg, 256, 0, stream>>>(xh, Wh + wsl, pWs + pl, out);
    finish_k<1><<<BB / 4, 256, 0, stream>>>(out, gWs + gl, gbs + gl, pbs + pl,
                                            bs + bsl, nullptr, xh);
    // layer 2 (no LN, in-place fp32)
    zero_k<<<zgrid, 256, 0, stream>>>(out);
    gemm_sk<<<gg, 256, 0, stream>>>(xh, Wh + 2 * wsl, pWs + 2 * pl, out);
    finish_k<0><<<BB / 4, 256, 0, stream>>>(out, gWs + 2 * gl, gbs + 2 * gl,
                                            pbs + 2 * pl, bs + 2 * bsl, out, nullptr);
}

// Round 4
// 1107.365 us; speedup vs baseline: 1.9861x; 1.9861x over previous
//
#include <hip/hip_runtime.h>
#include <math.h>

// Problem constants (B=10240, D=512, M=8, L=3)
#define BB   10240
#define DD   512
#define MM   8

typedef _Float16 h8 __attribute__((ext_vector_type(8)));
typedef float    f4 __attribute__((ext_vector_type(4)));

// ---------------- fp32 -> fp16 convert (8 elems/thread) ----------------
__global__ void __launch_bounds__(256) cvt_f32_f16(const float* __restrict__ s,
                                                   _Float16* __restrict__ d, int n8) {
    int i = blockIdx.x * 256 + threadIdx.x;
    if (i >= n8) return;
    const float4* sp = (const float4*)s + (size_t)i * 2;
    float4 a = sp[0], b = sp[1];
    h8 o = { (_Float16)a.x, (_Float16)a.y, (_Float16)a.z, (_Float16)a.w,
             (_Float16)b.x, (_Float16)b.y, (_Float16)b.z, (_Float16)b.w };
    *(h8*)(d + (size_t)i * 8) = o;
}

// ---------------- no-LDS GEMM core ----------------
// accb[b,i] = sum_m pW[b,m] sum_j W[m,i,j] x[b,j]     (raw, fp32, plain stores)
// Tile BM=128 (rows b), BN=64 (cols i), full K in-block. 4 waves as 2x2:
// wm -> 64 rows (4 mt), wn -> 32 cols (2 nt). MFMA fragments loaded DIRECTLY
// from global (16B/lane, 64B segments/row) -- W slab (4 MB/layer) and x are
// L1/L2-hot, so no LDS staging and NO __syncthreads in the K-loop: compiler
// issues global loads with fine-grained vmcnt(N), latency hidden by unroll +
// 12 waves/CU. pW applied in-register to the A fragment (v_pk_mul_f16).
__global__ void __launch_bounds__(256, 3) gemm_nolds(
    const _Float16* __restrict__ xh,   // (B,512) fp16
    const _Float16* __restrict__ Wh,   // (8,512,512) fp16
    const float*  __restrict__ pW,     // (B,8)
    float* __restrict__ accb)          // (B,512) fp32 raw dot
{
    const int tid  = threadIdx.x;
    const int lane = tid & 63;
    const int w    = tid >> 6;
    const int wm   = w >> 1, wn = w & 1;
    const int ln16 = lane & 15, quad = lane >> 4;
    const int bn0  = blockIdx.x * 64;
    const int bm0  = blockIdx.y * 128;

    // per-lane pW for this wave's 4 A-row groups (row = bm0+wm*64+mt*16+ln16)
    _Float16 pwh[4][8];
    #pragma unroll
    for (int mt = 0; mt < 4; ++mt) {
        const float* pp = pW + (size_t)(bm0 + wm * 64 + mt * 16 + ln16) * MM;
        float4 p0 = *(const float4*)pp;
        float4 p1 = *(const float4*)(pp + 4);
        pwh[mt][0] = (_Float16)p0.x; pwh[mt][1] = (_Float16)p0.y;
        pwh[mt][2] = (_Float16)p0.z; pwh[mt][3] = (_Float16)p0.w;
        pwh[mt][4] = (_Float16)p1.x; pwh[mt][5] = (_Float16)p1.y;
        pwh[mt][6] = (_Float16)p1.z; pwh[mt][7] = (_Float16)p1.w;
    }

    // fragment row base pointers (lane-dependent)
    const _Float16* arow[4];
    #pragma unroll
    for (int mt = 0; mt < 4; ++mt)
        arow[mt] = xh + (size_t)(bm0 + wm * 64 + mt * 16 + ln16) * DD;
    const _Float16* brow[2];
    #pragma unroll
    for (int nt = 0; nt < 2; ++nt)
        brow[nt] = Wh + (size_t)(bn0 + wn * 32 + nt * 16 + ln16) * DD;

    f4 acc[4][2] = {};

    for (int jc = 0; jc < 8; ++jc) {
        const int k0 = jc * 64 + quad * 8;     // lane's k offset within row

        h8 af[2][4];                           // A frags, reused across all 8 m
        #pragma unroll
        for (int ks = 0; ks < 2; ++ks)
            #pragma unroll
            for (int mt = 0; mt < 4; ++mt)
                af[ks][mt] = *(const h8*)(arow[mt] + k0 + ks * 32);

        #pragma unroll
        for (int mi = 0; mi < 8; ++mi) {
            h8 bf[2][2];
            #pragma unroll
            for (int ks = 0; ks < 2; ++ks)
                #pragma unroll
                for (int nt = 0; nt < 2; ++nt)
                    bf[ks][nt] = *(const h8*)(brow[nt] + (size_t)mi * (DD * DD)
                                              + k0 + ks * 32);
            #pragma unroll
            for (int ks = 0; ks < 2; ++ks)
                #pragma unroll
                for (int mt = 0; mt < 4; ++mt) {
                    h8 as = af[ks][mt] * pwh[mt][mi];   // v_pk_mul_f16 x4
                    #pragma unroll
                    for (int nt = 0; nt < 2; ++nt)
                        acc[mt][nt] = __builtin_amdgcn_mfma_f32_16x16x32_f16(
                            as, bf[ks][nt], acc[mt][nt], 0, 0, 0);
                }
        }
    }

    // ---- plain stores of raw acc (each element written exactly once) ----
    const int i0 = bn0 + wn * 32 + ln16;
    const int i1 = i0 + 16;
    #pragma unroll
    for (int mt = 0; mt < 4; ++mt)
        #pragma unroll
        for (int r = 0; r < 4; ++r) {
            int b = bm0 + wm * 64 + mt * 16 + quad * 4 + r;
            accb[(size_t)b * DD + i0] = acc[mt][0][r];
            accb[(size_t)b * DD + i1] = acc[mt][1][r];
        }
}

// ---------------- finish: gate + bias (+ LayerNorm + ELU) ----------------
// h[b,i] = gW[b,i]*acc[b,i] + gb[b,i]*sum_m pb[b,m]*bs[m,i]
// DO_LN: LN(no affine)+ELU -> fp16 outh; else fp32 outf (may alias acc).
template <int DO_LN>
__global__ void __launch_bounds__(256) finish_k(
    const float* __restrict__ acc,   // (B,512) raw dot
    const float* __restrict__ gW,    // (B,512)
    const float* __restrict__ gb,    // (B,512)
    const float* __restrict__ pb,    // (B,8)
    const float* __restrict__ bsv,   // (8,512)
    float* __restrict__ outf, _Float16* __restrict__ outh) {
    const int w    = threadIdx.x >> 6;
    const int lane = threadIdx.x & 63;
    const int row  = blockIdx.x * 4 + w;
    const int i0   = lane * 8;

    const float* ap = acc + (size_t)row * DD + i0;
    float a[8];
    *(float4*)a       = *(const float4*)ap;
    *(float4*)(a + 4) = *(const float4*)(ap + 4);

    float4 q0 = *(const float4*)(pb + (size_t)row * MM);
    float4 q1 = *(const float4*)(pb + (size_t)row * MM + 4);
    float pbv[8] = { q0.x, q0.y, q0.z, q0.w, q1.x, q1.y, q1.z, q1.w };

    float bias[8] = {};
    #pragma unroll
    for (int m = 0; m < 8; ++m) {
        const float* bp = bsv + m * DD + i0;
        float4 b0 = *(const float4*)bp, b1 = *(const float4*)(bp + 4);
        float bb[8] = { b0.x, b0.y, b0.z, b0.w, b1.x, b1.y, b1.z, b1.w };
        #pragma unroll
        for (int j = 0; j < 8; ++j) bias[j] += pbv[m] * bb[j];
    }

    const float* gwp = gW + (size_t)row * DD + i0;
    const float* gbp = gb + (size_t)row * DD + i0;
    float4 w0 = *(const float4*)gwp, w1 = *(const float4*)(gwp + 4);
    float4 g0 = *(const float4*)gbp, g1 = *(const float4*)(gbp + 4);
    float gw[8] = { w0.x, w0.y, w0.z, w0.w, w1.x, w1.y, w1.z, w1.w };
    float gg[8] = { g0.x, g0.y, g0.z, g0.w, g1.x, g1.y, g1.z, g1.w };

    float h[8];
    #pragma unroll
    for (int j = 0; j < 8; ++j) h[j] = gw[j] * a[j] + gg[j] * bias[j];

    if (DO_LN) {
        float s = 0.f, q = 0.f;
        #pragma unroll
        for (int j = 0; j < 8; ++j) { s += h[j]; q += h[j] * h[j]; }
        #pragma unroll
        for (int off = 1; off < 64; off <<= 1) {
            s += __shfl_xor(s, off);
            q += __shfl_xor(q, off);
        }
        float mu   = s * (1.0f / 512.0f);
        float var  = q * (1.0f / 512.0f) - mu * mu;
        float rstd = rsqrtf(var + 1e-5f);
        h8 o;
        #pragma unroll
        for (int j = 0; j < 8; ++j) {
            float t = (h[j] - mu) * rstd;
            t = t > 0.0f ? t : expm1f(t);
            o[j] = (_Float16)t;
        }
        *(h8*)(outh + (size_t)row * DD + i0) = o;
    } else {
        float* op = outf + (size_t)row * DD + i0;
        *(float4*)op       = make_float4(h[0], h[1], h[2], h[3]);
        *(float4*)(op + 4) = make_float4(h[4], h[5], h[6], h[7]);
    }
}

extern "C" void kernel_launch(void* const* d_in, const int* in_sizes, int n_in,
                              void* d_out, int out_size, void* d_ws, size_t ws_size,
                              hipStream_t stream) {
    const float* x   = (const float*)d_in[0];   // (B,512)
    const float* Ws  = (const float*)d_in[1];   // (3,8,512,512)
    const float* bs  = (const float*)d_in[2];   // (3,8,512)
    const float* pWs = (const float*)d_in[3];   // (3,B,8)
    const float* pbs = (const float*)d_in[4];   // (3,B,8)
    const float* gWs = (const float*)d_in[5];   // (3,B,512,1)
    const float* gbs = (const float*)d_in[6];   // (3,B,512)
    float* out = (float*)d_out;                 // (B,512); doubles as fp32 acc

    // workspace: Wh 12.58 MB + xh 10.49 MB = 23.1 MB
    _Float16* Wh = (_Float16*)d_ws;
    _Float16* xh = Wh + (size_t)3 * MM * DD * DD;

    const int wsl = MM * DD * DD;
    const int bsl = MM * DD;
    const int pl  = BB * MM;
    const int gl  = BB * DD;

    cvt_f32_f16<<<3072, 256, 0, stream>>>(Ws, Wh, 786432);   // 3*8*512*512/8
    cvt_f32_f16<<<2560, 256, 0, stream>>>(x, xh, 655360);    // B*512/8

    dim3 gg(DD / 64, BB / 128);          // (8, 80) = 640 blocks

    // layer 0
    gemm_nolds<<<gg, 256, 0, stream>>>(xh, Wh, pWs, out);
    finish_k<1><<<BB / 4, 256, 0, stream>>>(out, gWs, gbs, pbs, bs, nullptr, xh);
    // layer 1
    gemm_nolds<<<gg, 256, 0, stream>>>(xh, Wh + wsl, pWs + pl, out);
    finish_k<1><<<BB / 4, 256, 0, stream>>>(out, gWs + gl, gbs + gl, pbs + pl,
                                            bs + bsl, nullptr, xh);
    // layer 2 (no LN, in-place fp32)
    gemm_nolds<<<gg, 256, 0, stream>>>(xh, Wh + 2 * wsl, pWs + 2 * pl, out);
    finish_k<0><<<BB / 4, 256, 0, stream>>>(out, gWs + 2 * gl, gbs + 2 * gl,
                                            pbs + 2 * pl, bs + 2 * bsl, out, nullptr);
}

// Round 5
// 787.542 us; speedup vs baseline: 2.7926x; 1.4061x over previous
//
#include <hip/hip_runtime.h>
#include <math.h>

// Problem constants (B=10240, D=512, M=8, L=3)
#define BB   10240
#define DD   512
#define MM   8

typedef _Float16 h8 __attribute__((ext_vector_type(8)));
typedef float    f4 __attribute__((ext_vector_type(4)));

// ---------------- fp32 -> fp16 convert (8 elems/thread) ----------------
__global__ void __launch_bounds__(256) cvt_f32_f16(const float* __restrict__ s,
                                                   _Float16* __restrict__ d, int n8) {
    int i = blockIdx.x * 256 + threadIdx.x;
    if (i >= n8) return;
    const float4* sp = (const float4*)s + (size_t)i * 2;
    float4 a = sp[0], b = sp[1];
    h8 o = { (_Float16)a.x, (_Float16)a.y, (_Float16)a.z, (_Float16)a.w,
             (_Float16)b.x, (_Float16)b.y, (_Float16)b.z, (_Float16)b.w };
    *(h8*)(d + (size_t)i * 8) = o;
}

// ---------------- no-LDS GEMM core, XCD-pinned columns ----------------
// accb[b,i] = sum_m pW[b,m] sum_j W[m,i,j] x[b,j]   (raw fp32, plain stores)
// grid (8, 80) x-fastest => linear blk % 8 == col-tile == XCD (round-robin
// dispatch): each XCD touches ONE 64-col W slice (512 KB, L2-resident).
// 512 threads = 8 waves as 4 (rows) x 2 (cols); BM=128, BN=64; full K=4096
// in-block. MFMA fragments loaded directly from global (16 B/lane, 64 B
// segments; W rows shared by 4 wm-waves -> L1 dedup). ZERO __syncthreads:
// compiler schedules loads with fine-grained vmcnt across the unrolled loop.
// pW applied in-register to A frags (v_pk_mul_f16).
__global__ void __launch_bounds__(512, 4) gemm_nolds(
    const _Float16* __restrict__ xh,   // (B,512) fp16
    const _Float16* __restrict__ Wh,   // (8,512,512) fp16
    const float*  __restrict__ pW,     // (B,8)
    float* __restrict__ accb)          // (B,512) fp32 raw dot
{
    const int tid  = threadIdx.x;
    const int lane = tid & 63;
    const int w    = tid >> 6;         // 0..7
    const int wm   = w >> 1;           // 0..3: 32-row group
    const int wn   = w & 1;            // 0..1: 32-col group
    const int ln16 = lane & 15, quad = lane >> 4;
    const int bn0  = blockIdx.x * 64;
    const int bm0  = blockIdx.y * 128;

    // per-lane pW for this wave's 2 A-row groups (row = bm0+wm*32+mt*16+ln16)
    _Float16 pwh[2][8];
    #pragma unroll
    for (int mt = 0; mt < 2; ++mt) {
        const float* pp = pW + (size_t)(bm0 + wm * 32 + mt * 16 + ln16) * MM;
        float4 p0 = *(const float4*)pp;
        float4 p1 = *(const float4*)(pp + 4);
        pwh[mt][0] = (_Float16)p0.x; pwh[mt][1] = (_Float16)p0.y;
        pwh[mt][2] = (_Float16)p0.z; pwh[mt][3] = (_Float16)p0.w;
        pwh[mt][4] = (_Float16)p1.x; pwh[mt][5] = (_Float16)p1.y;
        pwh[mt][6] = (_Float16)p1.z; pwh[mt][7] = (_Float16)p1.w;
    }

    const _Float16* arow[2];
    #pragma unroll
    for (int mt = 0; mt < 2; ++mt)
        arow[mt] = xh + (size_t)(bm0 + wm * 32 + mt * 16 + ln16) * DD;
    const _Float16* brow[2];
    #pragma unroll
    for (int nt = 0; nt < 2; ++nt)
        brow[nt] = Wh + (size_t)(bn0 + wn * 32 + nt * 16 + ln16) * DD;

    f4 acc[2][2] = {};

    #pragma unroll
    for (int jc = 0; jc < 8; ++jc) {
        const int k0 = jc * 64 + quad * 8;   // lane's k offset within a row

        h8 af[2][2];                         // [ks][mt], reused across 8 m
        #pragma unroll
        for (int ks = 0; ks < 2; ++ks)
            #pragma unroll
            for (int mt = 0; mt < 2; ++mt)
                af[ks][mt] = *(const h8*)(arow[mt] + k0 + ks * 32);

        #pragma unroll
        for (int mi = 0; mi < 8; ++mi) {
            h8 bf[2][2];                     // [ks][nt]
            #pragma unroll
            for (int ks = 0; ks < 2; ++ks)
                #pragma unroll
                for (int nt = 0; nt < 2; ++nt)
                    bf[ks][nt] = *(const h8*)(brow[nt] + (size_t)mi * (DD * DD)
                                              + k0 + ks * 32);
            #pragma unroll
            for (int ks = 0; ks < 2; ++ks)
                #pragma unroll
                for (int mt = 0; mt < 2; ++mt) {
                    h8 as = af[ks][mt] * pwh[mt][mi];   // v_pk_mul_f16 x4
                    #pragma unroll
                    for (int nt = 0; nt < 2; ++nt)
                        acc[mt][nt] = __builtin_amdgcn_mfma_f32_16x16x32_f16(
                            as, bf[ks][nt], acc[mt][nt], 0, 0, 0);
                }
        }
    }

    // ---- plain stores of raw acc (each element written exactly once) ----
    const int i0 = bn0 + wn * 32 + ln16;
    const int i1 = i0 + 16;
    #pragma unroll
    for (int mt = 0; mt < 2; ++mt)
        #pragma unroll
        for (int r = 0; r < 4; ++r) {
            int b = bm0 + wm * 32 + mt * 16 + quad * 4 + r;
            accb[(size_t)b * DD + i0] = acc[mt][0][r];
            accb[(size_t)b * DD + i1] = acc[mt][1][r];
        }
}

// ---------------- finish: gate + bias (+ LayerNorm + ELU) ----------------
// h[b,i] = gW[b,i]*acc[b,i] + gb[b,i]*sum_m pb[b,m]*bs[m,i]
// DO_LN: LN(no affine)+ELU -> fp16 outh; else fp32 outf (may alias acc).
template <int DO_LN>
__global__ void __launch_bounds__(256) finish_k(
    const float* __restrict__ acc,   // (B,512) raw dot
    const float* __restrict__ gW,    // (B,512)
    const float* __restrict__ gb,    // (B,512)
    const float* __restrict__ pb,    // (B,8)
    const float* __restrict__ bsv,   // (8,512)
    float* __restrict__ outf, _Float16* __restrict__ outh) {
    const int w    = threadIdx.x >> 6;
    const int lane = threadIdx.x & 63;
    const int row  = blockIdx.x * 4 + w;
    const int i0   = lane * 8;

    const float* ap = acc + (size_t)row * DD + i0;
    float a[8];
    *(float4*)a       = *(const float4*)ap;
    *(float4*)(a + 4) = *(const float4*)(ap + 4);

    float4 q0 = *(const float4*)(pb + (size_t)row * MM);
    float4 q1 = *(const float4*)(pb + (size_t)row * MM + 4);
    float pbv[8] = { q0.x, q0.y, q0.z, q0.w, q1.x, q1.y, q1.z, q1.w };

    float bias[8] = {};
    #pragma unroll
    for (int m = 0; m < 8; ++m) {
        const float* bp = bsv + m * DD + i0;
        float4 b0 = *(const float4*)bp, b1 = *(const float4*)(bp + 4);
        float bb[8] = { b0.x, b0.y, b0.z, b0.w, b1.x, b1.y, b1.z, b1.w };
        #pragma unroll
        for (int j = 0; j < 8; ++j) bias[j] += pbv[m] * bb[j];
    }

    const float* gwp = gW + (size_t)row * DD + i0;
    const float* gbp = gb + (size_t)row * DD + i0;
    float4 w0 = *(const float4*)gwp, w1 = *(const float4*)(gwp + 4);
    float4 g0 = *(const float4*)gbp, g1 = *(const float4*)(gbp + 4);
    float gw[8] = { w0.x, w0.y, w0.z, w0.w, w1.x, w1.y, w1.z, w1.w };
    float gg[8] = { g0.x, g0.y, g0.z, g0.w, g1.x, g1.y, g1.z, g1.w };

    float h[8];
    #pragma unroll
    for (int j = 0; j < 8; ++j) h[j] = gw[j] * a[j] + gg[j] * bias[j];

    if (DO_LN) {
        float s = 0.f, q = 0.f;
        #pragma unroll
        for (int j = 0; j < 8; ++j) { s += h[j]; q += h[j] * h[j]; }
        #pragma unroll
        for (int off = 1; off < 64; off <<= 1) {
            s += __shfl_xor(s, off);
            q += __shfl_xor(q, off);
        }
        float mu   = s * (1.0f / 512.0f);
        float var  = q * (1.0f / 512.0f) - mu * mu;
        float rstd = rsqrtf(var + 1e-5f);
        h8 o;
        #pragma unroll
        for (int j = 0; j < 8; ++j) {
            float t = (h[j] - mu) * rstd;
            t = t > 0.0f ? t : expm1f(t);
            o[j] = (_Float16)t;
        }
        *(h8*)(outh + (size_t)row * DD + i0) = o;
    } else {
        float* op = outf + (size_t)row * DD + i0;
        *(float4*)op       = make_float4(h[0], h[1], h[2], h[3]);
        *(float4*)(op + 4) = make_float4(h[4], h[5], h[6], h[7]);
    }
}

extern "C" void kernel_launch(void* const* d_in, const int* in_sizes, int n_in,
                              void* d_out, int out_size, void* d_ws, size_t ws_size,
                              hipStream_t stream) {
    const float* x   = (const float*)d_in[0];   // (B,512)
    const float* Ws  = (const float*)d_in[1];   // (3,8,512,512)
    const float* bs  = (const float*)d_in[2];   // (3,8,512)
    const float* pWs = (const float*)d_in[3];   // (3,B,8)
    const float* pbs = (const float*)d_in[4];   // (3,B,8)
    const float* gWs = (const float*)d_in[5];   // (3,B,512,1)
    const float* gbs = (const float*)d_in[6];   // (3,B,512)
    float* out = (float*)d_out;                 // (B,512); doubles as fp32 acc

    // workspace: Wh 12.58 MB + xh 10.49 MB = 23.1 MB
    _Float16* Wh = (_Float16*)d_ws;
    _Float16* xh = Wh + (size_t)3 * MM * DD * DD;

    const int wsl = MM * DD * DD;
    const int bsl = MM * DD;
    const int pl  = BB * MM;
    const int gl  = BB * DD;

    cvt_f32_f16<<<3072, 256, 0, stream>>>(Ws, Wh, 786432);   // 3*8*512*512/8
    cvt_f32_f16<<<2560, 256, 0, stream>>>(x, xh, 655360);    // B*512/8

    dim3 gg(DD / 64, BB / 128);          // (8, 80): x-fastest => col == XCD

    // layer 0
    gemm_nolds<<<gg, 512, 0, stream>>>(xh, Wh, pWs, out);
    finish_k<1><<<BB / 4, 256, 0, stream>>>(out, gWs, gbs, pbs, bs, nullptr, xh);
    // layer 1
    gemm_nolds<<<gg, 512, 0, stream>>>(xh, Wh + wsl, pWs + pl, out);
    finish_k<1><<<BB / 4, 256, 0, stream>>>(out, gWs + gl, gbs + gl, pbs + pl,
                                            bs + bsl, nullptr, xh);
    // layer 2 (no LN, in-place fp32)
    gemm_nolds<<<gg, 512, 0, stream>>>(xh, Wh + 2 * wsl, pWs + 2 * pl, out);
    finish_k<0><<<BB / 4, 256, 0, stream>>>(out, gWs + 2 * gl, gbs + 2 * gl,
                                            pbs + 2 * pl, bs + 2 * bsl, out, nullptr);
}

// Round 6
// 756.239 us; speedup vs baseline: 2.9082x; 1.0414x over previous
//
#include <hip/hip_runtime.h>
#include <math.h>

// Problem constants (B=10240, D=512, M=8, L=3)
#define BB   10240
#define DD   512
#define MM   8

typedef _Float16 h8 __attribute__((ext_vector_type(8)));
typedef float    f4 __attribute__((ext_vector_type(4)));

// ---------------- fp32 -> fp16 convert (8 elems/thread) ----------------
__global__ void __launch_bounds__(256) cvt_f32_f16(const float* __restrict__ s,
                                                   _Float16* __restrict__ d, int n8) {
    int i = blockIdx.x * 256 + threadIdx.x;
    if (i >= n8) return;
    const float4* sp = (const float4*)s + (size_t)i * 2;
    float4 a = sp[0], b = sp[1];
    h8 o = { (_Float16)a.x, (_Float16)a.y, (_Float16)a.z, (_Float16)a.w,
             (_Float16)b.x, (_Float16)b.y, (_Float16)b.z, (_Float16)b.w };
    *(h8*)(d + (size_t)i * 8) = o;
}

// ---------------- no-LDS GEMM, XCD-pinned, register-double-buffered ----------------
// accb[b,i] = sum_m pW[b,m] sum_j W[m,i,j] x[b,j]   (raw fp32, plain stores)
// grid (8, 80) x-fastest: linear blk % 8 == col-tile == XCD -> per-XCD W
// working set 512 KB (L2-resident; R5 verified FETCH 698->45 MB).
// Block 256 thr = 4 waves stacked on ROWS: block tile 128x64, wave tile 32x64
// (mt=2, nt=4) -- all 4 waves read the SAME B frags (L1 dedup).
// ZERO barriers. B batch (8x16B) explicitly double-buffered distance-1, A
// chunk prefetched a full 8-mi lap early -> ~10 loads in flight per wave so
// the ~200cyc L1/L2 latency is covered (R5 failure mode: VGPR=64, JIT loads).
// pW applied in-register to A frags (v_pk_mul_f16; A-side only: cost
// independent of nt, so nt=4 halves its relative issue share vs R5).
__global__ void __launch_bounds__(256, 3) gemm_nolds(
    const _Float16* __restrict__ xh,   // (B,512) fp16
    const _Float16* __restrict__ Wh,   // (8,512,512) fp16
    const float*  __restrict__ pW,     // (B,8)
    float* __restrict__ accb)          // (B,512) fp32 raw dot
{
    const int tid  = threadIdx.x;
    const int lane = tid & 63;
    const int wm   = tid >> 6;         // 0..3: 32-row group (waves stack on rows)
    const int ln16 = lane & 15, quad = lane >> 4;
    const int bn0  = blockIdx.x * 64;
    const int bm0  = blockIdx.y * 128;

    // per-lane pW for this wave's 2 A-row groups (row = bm0+wm*32+mt*16+ln16)
    _Float16 pwh[2][8];
    #pragma unroll
    for (int mt = 0; mt < 2; ++mt) {
        const float* pp = pW + (size_t)(bm0 + wm * 32 + mt * 16 + ln16) * MM;
        float4 p0 = *(const float4*)pp;
        float4 p1 = *(const float4*)(pp + 4);
        pwh[mt][0] = (_Float16)p0.x; pwh[mt][1] = (_Float16)p0.y;
        pwh[mt][2] = (_Float16)p0.z; pwh[mt][3] = (_Float16)p0.w;
        pwh[mt][4] = (_Float16)p1.x; pwh[mt][5] = (_Float16)p1.y;
        pwh[mt][6] = (_Float16)p1.z; pwh[mt][7] = (_Float16)p1.w;
    }

    const _Float16* arow[2];
    #pragma unroll
    for (int mt = 0; mt < 2; ++mt)
        arow[mt] = xh + (size_t)(bm0 + wm * 32 + mt * 16 + ln16) * DD;
    const _Float16* brow[4];
    #pragma unroll
    for (int nt = 0; nt < 4; ++nt)
        brow[nt] = Wh + (size_t)(bn0 + nt * 16 + ln16) * DD;

    h8 bbuf[2][2][4];   // [buf][ks][nt]  (64 VGPR)
    h8 abuf[2][2][2];   // [buf][ks][mt]  (32 VGPR)

    auto loadB = [&](int buf, int t) {
        const int jc = t >> 3, mi = t & 7;
        const size_t off = (size_t)mi * (DD * DD) + jc * 64 + quad * 8;
        #pragma unroll
        for (int ks = 0; ks < 2; ++ks)
            #pragma unroll
            for (int nt = 0; nt < 4; ++nt)
                bbuf[buf][ks][nt] = *(const h8*)(brow[nt] + off + ks * 32);
    };
    auto loadA = [&](int buf, int jc) {
        const int k0 = jc * 64 + quad * 8;
        #pragma unroll
        for (int ks = 0; ks < 2; ++ks)
            #pragma unroll
            for (int mt = 0; mt < 2; ++mt)
                abuf[buf][ks][mt] = *(const h8*)(arow[mt] + k0 + ks * 32);
    };

    f4 acc[2][4] = {};

    loadA(0, 0);
    loadB(0, 0);

    #pragma unroll
    for (int jc = 0; jc < 8; ++jc) {
        #pragma unroll
        for (int mi = 0; mi < 8; ++mi) {
            const int t = jc * 8 + mi;
            if (t < 63) loadB((t + 1) & 1, t + 1);          // distance-1 B prefetch
            if (mi == 0 && jc < 7) loadA((jc + 1) & 1, jc + 1); // A a full lap early

            #pragma unroll
            for (int ks = 0; ks < 2; ++ks)
                #pragma unroll
                for (int mt = 0; mt < 2; ++mt) {
                    h8 as = abuf[jc & 1][ks][mt] * pwh[mt][mi];  // v_pk_mul_f16 x4
                    #pragma unroll
                    for (int nt = 0; nt < 4; ++nt)
                        acc[mt][nt] = __builtin_amdgcn_mfma_f32_16x16x32_f16(
                            as, bbuf[t & 1][ks][nt], acc[mt][nt], 0, 0, 0);
                }
        }
    }

    // ---- plain stores of raw acc (each element written exactly once) ----
    #pragma unroll
    for (int mt = 0; mt < 2; ++mt)
        #pragma unroll
        for (int nt = 0; nt < 4; ++nt) {
            const int i = bn0 + nt * 16 + ln16;
            #pragma unroll
            for (int r = 0; r < 4; ++r) {
                int b = bm0 + wm * 32 + mt * 16 + quad * 4 + r;
                accb[(size_t)b * DD + i] = acc[mt][nt][r];
            }
        }
}

// ---------------- finish: gate + bias (+ LayerNorm + ELU) ----------------
// h[b,i] = gW[b,i]*acc[b,i] + gb[b,i]*sum_m pb[b,m]*bs[m,i]
// DO_LN: LN(no affine)+ELU -> fp16 outh; else fp32 outf (may alias acc).
template <int DO_LN>
__global__ void __launch_bounds__(256) finish_k(
    const float* __restrict__ acc,   // (B,512) raw dot
    const float* __restrict__ gW,    // (B,512)
    const float* __restrict__ gb,    // (B,512)
    const float* __restrict__ pb,    // (B,8)
    const float* __restrict__ bsv,   // (8,512)
    float* __restrict__ outf, _Float16* __restrict__ outh) {
    const int w    = threadIdx.x >> 6;
    const int lane = threadIdx.x & 63;
    const int row  = blockIdx.x * 4 + w;
    const int i0   = lane * 8;

    const float* ap = acc + (size_t)row * DD + i0;
    float a[8];
    *(float4*)a       = *(const float4*)ap;
    *(float4*)(a + 4) = *(const float4*)(ap + 4);

    float4 q0 = *(const float4*)(pb + (size_t)row * MM);
    float4 q1 = *(const float4*)(pb + (size_t)row * MM + 4);
    float pbv[8] = { q0.x, q0.y, q0.z, q0.w, q1.x, q1.y, q1.z, q1.w };

    float bias[8] = {};
    #pragma unroll
    for (int m = 0; m < 8; ++m) {
        const float* bp = bsv + m * DD + i0;
        float4 b0 = *(const float4*)bp, b1 = *(const float4*)(bp + 4);
        float bb[8] = { b0.x, b0.y, b0.z, b0.w, b1.x, b1.y, b1.z, b1.w };
        #pragma unroll
        for (int j = 0; j < 8; ++j) bias[j] += pbv[m] * bb[j];
    }

    const float* gwp = gW + (size_t)row * DD + i0;
    const float* gbp = gb + (size_t)row * DD + i0;
    float4 w0 = *(const float4*)gwp, w1 = *(const float4*)(gwp + 4);
    float4 g0 = *(const float4*)gbp, g1 = *(const float4*)(gbp + 4);
    float gw[8] = { w0.x, w0.y, w0.z, w0.w, w1.x, w1.y, w1.z, w1.w };
    float gg[8] = { g0.x, g0.y, g0.z, g0.w, g1.x, g1.y, g1.z, g1.w };

    float h[8];
    #pragma unroll
    for (int j = 0; j < 8; ++j) h[j] = gw[j] * a[j] + gg[j] * bias[j];

    if (DO_LN) {
        float s = 0.f, q = 0.f;
        #pragma unroll
        for (int j = 0; j < 8; ++j) { s += h[j]; q += h[j] * h[j]; }
        #pragma unroll
        for (int off = 1; off < 64; off <<= 1) {
            s += __shfl_xor(s, off);
            q += __shfl_xor(q, off);
        }
        float mu   = s * (1.0f / 512.0f);
        float var  = q * (1.0f / 512.0f) - mu * mu;
        float rstd = rsqrtf(var + 1e-5f);
        h8 o;
        #pragma unroll
        for (int j = 0; j < 8; ++j) {
            float t = (h[j] - mu) * rstd;
            t = t > 0.0f ? t : expm1f(t);
            o[j] = (_Float16)t;
        }
        *(h8*)(outh + (size_t)row * DD + i0) = o;
    } else {
        float* op = outf + (size_t)row * DD + i0;
        *(float4*)op       = make_float4(h[0], h[1], h[2], h[3]);
        *(float4*)(op + 4) = make_float4(h[4], h[5], h[6], h[7]);
    }
}

extern "C" void kernel_launch(void* const* d_in, const int* in_sizes, int n_in,
                              void* d_out, int out_size, void* d_ws, size_t ws_size,
                              hipStream_t stream) {
    const float* x   = (const float*)d_in[0];   // (B,512)
    const float* Ws  = (const float*)d_in[1];   // (3,8,512,512)
    const float* bs  = (const float*)d_in[2];   // (3,8,512)
    const float* pWs = (const float*)d_in[3];   // (3,B,8)
    const float* pbs = (const float*)d_in[4];   // (3,B,8)
    const float* gWs = (const float*)d_in[5];   // (3,B,512,1)
    const float* gbs = (const float*)d_in[6];   // (3,B,512)
    float* out = (float*)d_out;                 // (B,512); doubles as fp32 acc

    // workspace: Wh 12.58 MB + xh 10.49 MB = 23.1 MB
    _Float16* Wh = (_Float16*)d_ws;
    _Float16* xh = Wh + (size_t)3 * MM * DD * DD;

    const int wsl = MM * DD * DD;
    const int bsl = MM * DD;
    const int pl  = BB * MM;
    const int gl  = BB * DD;

    cvt_f32_f16<<<3072, 256, 0, stream>>>(Ws, Wh, 786432);   // 3*8*512*512/8
    cvt_f32_f16<<<2560, 256, 0, stream>>>(x, xh, 655360);    // B*512/8

    dim3 gg(DD / 64, BB / 128);          // (8, 80): x-fastest => col == XCD

    // layer 0
    gemm_nolds<<<gg, 256, 0, stream>>>(xh, Wh, pWs, out);
    finish_k<1><<<BB / 4, 256, 0, stream>>>(out, gWs, gbs, pbs, bs, nullptr, xh);
    // layer 1
    gemm_nolds<<<gg, 256, 0, stream>>>(xh, Wh + wsl, pWs + pl, out);
    finish_k<1><<<BB / 4, 256, 0, stream>>>(out, gWs + gl, gbs + gl, pbs + pl,
                                            bs + bsl, nullptr, xh);
    // layer 2 (no LN, in-place fp32)
    gemm_nolds<<<gg, 256, 0, stream>>>(xh, Wh + 2 * wsl, pWs + 2 * pl, out);
    finish_k<0><<<BB / 4, 256, 0, stream>>>(out, gWs + 2 * gl, gbs + 2 * gl,
                                            pbs + 2 * pl, bs + 2 * bsl, out, nullptr);
}